// Round 10
// baseline (96.254 us; speedup 1.0000x reference)
//
#include <hip/hip_runtime.h>

// Problem constants (B, L, H, D, T) = (8, 4096, 8, 128, 128)
constexpr int B = 8;
constexpr int L = 4096;
constexpr int H = 8;
constexpr int D = 128;
constexpr int T = 128;

constexpr long long KV_ELEMS = (long long)B * L * H * D;  // floats per tensor
constexpr int TOTAL4 = (int)(KV_ELEMS / 4);               // 8,388,608 float4 per tensor

constexpr int NBLOCKS  = 2048;
constexpr int NTHREADS = 256;
// Each block covers 1024 consecutive float4 (16 KiB) per iteration: FOUR
// fully-coalesced 1-KiB-per-wave loads at adjacent offsets -> 4x per-wave MLP
// with zero page-locality cost. Per-iteration chip window = 32 MiB.
constexpr int PER_ITER = NBLOCKS * 1024;                  // 2,097,152 float4
constexpr int ITERS    = TOTAL4 / PER_ITER;               // 4 per tensor

// native clang vector type — __builtin_nontemporal_* requires this
typedef float f4 __attribute__((ext_vector_type(4)));

__device__ __forceinline__ f4 patch_sel(f4 v, int i,
                                        const int* __restrict__ lengths,
                                        const int* __restrict__ new_lengths,
                                        const f4* __restrict__ nsrc)
{
    const int row = i >> 8;            // 256 float4 per (b,p) row
    const int b   = row >> 12;         // / L
    const int p   = row & (L - 1);
    const int l   = lengths[b];        // uniform scalar loads, L1-resident
    const int nl  = new_lengths[b];
    if (p >= l && p < l + nl) {        // wave-uniform, <=3% of rows
        v = nsrc[((b * T + (p - l)) << 8) + (i & 255)];
    }
    return v;
}

__global__ __launch_bounds__(256) void kv_fused_phased4(
    const f4* __restrict__ keys,
    const f4* __restrict__ values,
    const int* __restrict__ lengths,
    const f4* __restrict__ new_keys,
    const f4* __restrict__ new_values,
    const int* __restrict__ new_lengths,
    f4* __restrict__ out_k,
    f4* __restrict__ out_v,
    float* __restrict__ out_len)
{
    const int bofs = blockIdx.x * 1024 + (int)threadIdx.x;

    #pragma unroll 1
    for (int it = 0; it < 2 * ITERS; ++it) {
        const bool is_k = (it < ITERS);
        const f4* __restrict__ src  = is_k ? keys     : values;
        const f4* __restrict__ nsrc = is_k ? new_keys : new_values;
        f4* __restrict__ dst        = is_k ? out_k    : out_v;

        const int i0 = (it & (ITERS - 1)) * PER_ITER + bofs;

        // four independent fully-coalesced non-temporal loads (4x MLP)
        f4 va = __builtin_nontemporal_load(&src[i0]);
        f4 vb = __builtin_nontemporal_load(&src[i0 + 256]);
        f4 vc = __builtin_nontemporal_load(&src[i0 + 512]);
        f4 vd = __builtin_nontemporal_load(&src[i0 + 768]);

        va = patch_sel(va, i0,       lengths, new_lengths, nsrc);
        vb = patch_sel(vb, i0 + 256, lengths, new_lengths, nsrc);
        vc = patch_sel(vc, i0 + 512, lengths, new_lengths, nsrc);
        vd = patch_sel(vd, i0 + 768, lengths, new_lengths, nsrc);

        __builtin_nontemporal_store(va, &dst[i0]);
        __builtin_nontemporal_store(vb, &dst[i0 + 256]);
        __builtin_nontemporal_store(vc, &dst[i0 + 512]);
        __builtin_nontemporal_store(vd, &dst[i0 + 768]);
    }

    if (blockIdx.x == 0 && threadIdx.x < B) {
        const int bb = threadIdx.x;
        out_len[bb] = (float)(lengths[bb] + new_lengths[bb]);
    }
}

extern "C" void kernel_launch(void* const* d_in, const int* in_sizes, int n_in,
                              void* d_out, int out_size, void* d_ws, size_t ws_size,
                              hipStream_t stream)
{
    const f4* keys        = (const f4*)d_in[0];
    const f4* values      = (const f4*)d_in[1];
    const int* lengths    = (const int*)d_in[2];
    const f4* new_keys    = (const f4*)d_in[3];
    const f4* new_values  = (const f4*)d_in[4];
    const int* new_lengths= (const int*)d_in[5];

    float* out     = (float*)d_out;
    f4* out_k      = (f4*)out;
    f4* out_v      = (f4*)(out + KV_ELEMS);
    float* out_len = out + 2 * KV_ELEMS;

    kv_fused_phased4<<<NBLOCKS, NTHREADS, 0, stream>>>(keys, values, lengths,
                                                       new_keys, new_values, new_lengths,
                                                       out_k, out_v, out_len);
}

// Round 11
// 95.413 us; speedup vs baseline: 1.0088x; 1.0088x over previous
//
#include <hip/hip_runtime.h>

// Problem constants (B, L, H, D, T) = (8, 4096, 8, 128, 128)
constexpr int B = 8;
constexpr int L = 4096;
constexpr int H = 8;
constexpr int D = 128;
constexpr int T = 128;

constexpr long long KV_ELEMS = (long long)B * L * H * D;  // floats per tensor
constexpr int TOTAL4 = (int)(KV_ELEMS / 4);               // 8,388,608 float4 per tensor

constexpr int NBLOCKS  = 2048;
constexpr int NTHREADS = 256;
// Each block covers 512 consecutive float4 (8 KiB) per iteration: two
// fully-coalesced 1-KiB-per-wave loads at adjacent offsets -> 2x per-wave MLP
// with zero page-locality cost.  Per-iteration chip window = 16 MiB.
// (4x MLP measured WORSE: 96.25 vs 95.25 us — MLP saturates at 2x.)
constexpr int PER_ITER = NBLOCKS * 512;                   // 1,048,576 float4
constexpr int ITERS    = TOTAL4 / PER_ITER;               // 8 per tensor

// native clang vector type — __builtin_nontemporal_* requires this
typedef float f4 __attribute__((ext_vector_type(4)));

// ---------------------------------------------------------------------------
// Best configuration (R9, 95.25 us = 5.64 TB/s effective, 90% of the 2-stream
// copy ubench):
//  - temporal phase-split: all waves copy K first, then V -> ~2 concurrent
//    address streams chip-wide instead of 4 (R7: +3%)
//  - non-temporal loads+stores: single-use data, no LLC allocation (R6: +5%)
//  - 2x per-wave MLP at CONTIGUOUS addresses (R9: +2%; 8-MiB-strided batching
//    regressed 38% in R2, per-block private windows regressed 7% in R4)
//  - patch-select fused inline: wave-uniform predicate, free (R8 showed pure
//    copies run at the same per-byte rate)
// ---------------------------------------------------------------------------
__global__ __launch_bounds__(256) void kv_fused_phased2(
    const f4* __restrict__ keys,
    const f4* __restrict__ values,
    const int* __restrict__ lengths,
    const f4* __restrict__ new_keys,
    const f4* __restrict__ new_values,
    const int* __restrict__ new_lengths,
    f4* __restrict__ out_k,
    f4* __restrict__ out_v,
    float* __restrict__ out_len)
{
    const int tid  = (int)threadIdx.x;
    const int bofs = blockIdx.x * 512 + tid;

    #pragma unroll 1
    for (int it = 0; it < 2 * ITERS; ++it) {
        const bool is_k = (it < ITERS);
        const f4* __restrict__ src  = is_k ? keys     : values;
        const f4* __restrict__ nsrc = is_k ? new_keys : new_values;
        f4* __restrict__ dst        = is_k ? out_k    : out_v;

        const int i0 = (it & (ITERS - 1)) * PER_ITER + bofs;
        const int i1 = i0 + 256;

        // two independent fully-coalesced non-temporal loads (2x MLP)
        f4 va = __builtin_nontemporal_load(&src[i0]);
        f4 vb = __builtin_nontemporal_load(&src[i1]);

        // patch-select for row of i0 (wave-uniform: row fixed per instruction)
        {
            const int row = i0 >> 8;
            const int b   = row >> 12;
            const int p   = row & (L - 1);
            const int l   = lengths[b];
            const int nl  = new_lengths[b];
            if (p >= l && p < l + nl) {
                va = nsrc[((b * T + (p - l)) << 8) + (i0 & 255)];
            }
        }
        // patch-select for row of i1
        {
            const int row = i1 >> 8;
            const int b   = row >> 12;
            const int p   = row & (L - 1);
            const int l   = lengths[b];
            const int nl  = new_lengths[b];
            if (p >= l && p < l + nl) {
                vb = nsrc[((b * T + (p - l)) << 8) + (i1 & 255)];
            }
        }

        __builtin_nontemporal_store(va, &dst[i0]);
        __builtin_nontemporal_store(vb, &dst[i1]);
    }

    if (blockIdx.x == 0 && threadIdx.x < B) {
        const int bb = threadIdx.x;
        out_len[bb] = (float)(lengths[bb] + new_lengths[bb]);
    }
}

extern "C" void kernel_launch(void* const* d_in, const int* in_sizes, int n_in,
                              void* d_out, int out_size, void* d_ws, size_t ws_size,
                              hipStream_t stream)
{
    const f4* keys        = (const f4*)d_in[0];
    const f4* values      = (const f4*)d_in[1];
    const int* lengths    = (const int*)d_in[2];
    const f4* new_keys    = (const f4*)d_in[3];
    const f4* new_values  = (const f4*)d_in[4];
    const int* new_lengths= (const int*)d_in[5];

    float* out     = (float*)d_out;
    f4* out_k      = (f4*)out;
    f4* out_v      = (f4*)(out + KV_ELEMS);
    float* out_len = out + 2 * KV_ELEMS;

    kv_fused_phased2<<<NBLOCKS, NTHREADS, 0, stream>>>(keys, values, lengths,
                                                       new_keys, new_values, new_lengths,
                                                       out_k, out_v, out_len);
}